// Round 4
// baseline (305.774 us; speedup 1.0000x reference)
//
#include <hip/hip_runtime.h>
#include <hip/hip_bf16.h>
#include <cstdint>

#define B_  16
#define TP  4096
#define TQ  512
#define D2_ 256
#define TI 64
#define TJ 32
#define NJT (TQ / TJ)   // 16

typedef _Float16 f16x8 __attribute__((ext_vector_type(8)));
typedef _Float16 f16x4 __attribute__((ext_vector_type(4)));
typedef float    f32x4 __attribute__((ext_vector_type(4)));

// ---- fragment blob stash: G slice-3 (last 1KB of each 4KB row) of rows 0..8191 ----
__device__ __forceinline__ _Float16* frag_wptr(float* G, int b, int jt, int f, int lane) {
  return (_Float16*)G + ((size_t)((b * NJT + jt) * 32 + f)) * 2048 + 1536 + lane * 8;
}

// ---------------- kernel 0: build f16 B-fragments + udot ----------------
__global__ __launch_bounds__(256) void k_prep(const float* __restrict__ U,
                                              const float* __restrict__ w,
                                              const int* __restrict__ mq,
                                              float* __restrict__ G,
                                              float* __restrict__ udot) {
  __shared__ _Float16 T[TJ][264];
  const int b = blockIdx.y, jt = blockIdx.x;
  const int tid = threadIdx.x, lane = tid & 63, wv = tid >> 6;
  const int l15 = lane & 15, g = lane >> 4;

#pragma unroll
  for (int it = 0; it < 8; ++it) {
    int chunk = it * 256 + tid;
    int r = chunk >> 6, c = (chunk & 63) * 4;
    int row = b * TQ + jt * TJ + r;
    float qmv = (float)mq[row];
    f32x4 u = *(const f32x4*)&U[(size_t)row * D2_ + c];
    f16x4 v;
    v[0] = (_Float16)(u.x * qmv); v[1] = (_Float16)(u.y * qmv);
    v[2] = (_Float16)(u.z * qmv); v[3] = (_Float16)(u.w * qmv);
    *(f16x4*)&T[r][c] = v;
  }
  __syncthreads();

  {
    int r = tid >> 3, s = tid & 7;
    float p = 0.f;
#pragma unroll
    for (int e = 0; e < 32; ++e) p += (float)T[r][s * 32 + e] * w[D2_ + s * 32 + e];
    p += __shfl_xor(p, 1); p += __shfl_xor(p, 2); p += __shfl_xor(p, 4);
    if (s == 0) udot[b * TQ + jt * TJ + r] = p;
  }

#pragma unroll
  for (int q = 0; q < 8; ++q) {
    int f = wv * 8 + q;
    f16x8 v;
    if (f < 16) {
      int t = f >> 3, ks = f & 7;
      v = *(const f16x8*)&T[t * 16 + l15][ks * 32 + g * 8];
    } else {
      int n = f - 16;
#pragma unroll
      for (int e = 0; e < 8; ++e) v[e] = T[g * 8 + e][n * 16 + l15];
    }
    *(f16x8*)frag_wptr(G, b, jt, f, lane) = v;
  }
}

// ---------------- kernel 1: flash S/softmax/PV, deferred-rescale ----------------
__global__ __launch_bounds__(512, 4) void k_main(
    const float* __restrict__ H, const float* __restrict__ w,
    const int* __restrict__ mp, const int* __restrict__ mq,
    const float* __restrict__ udot,
    float* __restrict__ SmaxOut, float* __restrict__ G) {

  __shared__ char smem[48640];
  _Float16 (*A4)[16][264] = (_Float16(*)[16][264])smem;            // 33792 B
  _Float16 (*P)[16][40]   = (_Float16(*)[16][40])(smem + 33792);   // 10240 B
  float* hd_s   = (float*)(smem + 33792 + 10240);                  // 256 B
  float* udot_s = (float*)(smem + 33792 + 10240 + 256);            // 2048 B
  float* qm_s   = udot_s + 512;                                    // 2048 B
  _Float16 (*Uatt)[264] = (_Float16(*)[264])smem;                  // epilogue reuse

  const int b = blockIdx.y, i0 = blockIdx.x * TI;
  const int tid = threadIdx.x, lane = tid & 63, wv = tid >> 6;
  const int l15 = lane & 15, g = lane >> 4;
  const int pr = wv >> 1;        // pair: rows pr*16..+15
  const int h  = wv & 1;         // c-half for PV

  // hoist per-batch udot/qm to LDS
  udot_s[tid] = udot[b * TQ + tid];
  qm_s[tid]   = (float)mq[b * TQ + tid];

  // ---- prologue: pair-leader stages A = f16(Hm*w_hu), hdot ----
  if (h == 0) {
    const int rowg = i0 + pr * 16 + l15;
    const float* Hrow = H + ((size_t)b * TP + rowg) * D2_;
    const float pmr = (float)mp[b * TP + rowg];
    float hp = 0.f;
#pragma unroll
    for (int ks = 0; ks < 8; ++ks) {
      int c0 = ks * 32 + g * 8;
      f32x4 h0 = *(const f32x4*)&Hrow[c0];
      f32x4 h1 = *(const f32x4*)&Hrow[c0 + 4];
      f32x4 wh0 = *(const f32x4*)&w[c0];
      f32x4 wh1 = *(const f32x4*)&w[c0 + 4];
      f32x4 wu0 = *(const f32x4*)&w[2 * D2_ + c0];
      f32x4 wu1 = *(const f32x4*)&w[2 * D2_ + c0 + 4];
      h0 *= pmr; h1 *= pmr;
      f16x8 a;
      a[0] = (_Float16)(h0.x * wu0.x); a[1] = (_Float16)(h0.y * wu0.y);
      a[2] = (_Float16)(h0.z * wu0.z); a[3] = (_Float16)(h0.w * wu0.w);
      a[4] = (_Float16)(h1.x * wu1.x); a[5] = (_Float16)(h1.y * wu1.y);
      a[6] = (_Float16)(h1.z * wu1.z); a[7] = (_Float16)(h1.w * wu1.w);
      *(f16x8*)&A4[pr][l15][c0] = a;
      hp += h0.x * wh0.x + h0.y * wh0.y + h0.z * wh0.z + h0.w * wh0.w
          + h1.x * wh1.x + h1.y * wh1.y + h1.z * wh1.z + h1.w * wh1.w;
    }
    hp += __shfl_xor(hp, 16);
    hp += __shfl_xor(hp, 32);
    if (g == 0) hd_s[pr * 16 + l15] = hp;
  }
  __syncthreads();

  float hd[4];
#pragma unroll
  for (int reg = 0; reg < 4; ++reg) hd[reg] = hd_s[pr * 16 + g * 4 + reg];

  f32x4 Oacc[8];
#pragma unroll
  for (int n = 0; n < 8; ++n) Oacc[n] = {0.f, 0.f, 0.f, 0.f};
  f32x4 Lacc = {0.f, 0.f, 0.f, 0.f};
  float m_run[4]  = {-1e30f, -1e30f, -1e30f, -1e30f};
  float m_true[4] = {-1e30f, -1e30f, -1e30f, -1e30f};

  f16x8 ones;
#pragma unroll
  for (int e = 0; e < 8; ++e) ones[e] = (_Float16)1.0f;

  const _Float16* Gf = (const _Float16*)G;

  for (int jt = 0; jt < NJT; ++jt) {
    const _Float16* fb = Gf + ((size_t)((b * NJT + jt) * 32)) * 2048 + 1536 + lane * 8;

    // ---- S: 16 rows x 32 cols ----
    f32x4 Sacc[2];
    Sacc[0] = {0.f, 0.f, 0.f, 0.f}; Sacc[1] = {0.f, 0.f, 0.f, 0.f};
#pragma unroll
    for (int ks = 0; ks < 8; ++ks) {
      f16x8 af = *(const f16x8*)&A4[pr][l15][ks * 32 + g * 8];
      f16x8 b0 = *(const f16x8*)(fb + (size_t)ks * 2048);
      f16x8 b1 = *(const f16x8*)(fb + (size_t)(8 + ks) * 2048);
      Sacc[0] = __builtin_amdgcn_mfma_f32_16x16x32_f16(af, b0, Sacc[0], 0, 0, 0);
      Sacc[1] = __builtin_amdgcn_mfma_f32_16x16x32_f16(af, b1, Sacc[1], 0, 0, 0);
    }

    // prefetch PV fragments (hide L2 latency under softmax)
    f16x8 uf[8];
#pragma unroll
    for (int n = 0; n < 8; ++n)
      uf[n] = *(const f16x8*)(fb + (size_t)(16 + h * 8 + n) * 2048);

    // ---- bias + deferred-rescale online softmax ----
    float ud[2], qv[2];
#pragma unroll
    for (int t = 0; t < 2; ++t) {
      ud[t] = udot_s[jt * TJ + t * 16 + l15];
      qv[t] = qm_s[jt * TJ + t * 16 + l15];
    }
    float lmax[4];
#pragma unroll
    for (int reg = 0; reg < 4; ++reg) {
      float v0 = Sacc[0][reg] + hd[reg] + ud[0];
      float v1 = Sacc[1][reg] + hd[reg] + ud[1];
      Sacc[0][reg] = v0; Sacc[1][reg] = v1;
      lmax[reg] = fmaxf(v0, v1);
      m_true[reg] = fmaxf(m_true[reg], lmax[reg]);
    }
    float d = fmaxf(fmaxf(lmax[0] - m_run[0], lmax[1] - m_run[1]),
                    fmaxf(lmax[2] - m_run[2], lmax[3] - m_run[3]));
    if (__any(d > 8.0f)) {
      float tmax[4] = {lmax[0], lmax[1], lmax[2], lmax[3]};
#pragma unroll
      for (int o = 1; o < 16; o <<= 1)
#pragma unroll
        for (int reg = 0; reg < 4; ++reg)
          tmax[reg] = fmaxf(tmax[reg], __shfl_xor(tmax[reg], o));
#pragma unroll
      for (int reg = 0; reg < 4; ++reg) {
        float mn = fmaxf(m_run[reg], tmax[reg]);
        float sc = __expf(m_run[reg] - mn);
        m_run[reg] = mn;
        Lacc[reg] *= sc;
#pragma unroll
        for (int n = 0; n < 8; ++n) Oacc[n][reg] *= sc;
      }
    }

#pragma unroll
    for (int t = 0; t < 2; ++t)
#pragma unroll
      for (int reg = 0; reg < 4; ++reg) {
        float p = qv[t] * __expf(Sacc[t][reg] - m_run[reg]);
        P[wv][g * 4 + reg][t * 16 + l15] = (_Float16)p;
      }

    // ---- PV + row-sum-via-MFMA ----
    f16x8 pf = *(const f16x8*)&P[wv][l15][g * 8];
    Lacc = __builtin_amdgcn_mfma_f32_16x16x32_f16(pf, ones, Lacc, 0, 0, 0);
#pragma unroll
    for (int n = 0; n < 8; ++n)
      Oacc[n] = __builtin_amdgcn_mfma_f32_16x16x32_f16(pf, uf[n], Oacc[n], 0, 0, 0);
  }

  // ---- final true-max reduce + Smax out ----
#pragma unroll
  for (int o = 1; o < 16; o <<= 1)
#pragma unroll
    for (int reg = 0; reg < 4; ++reg)
      m_true[reg] = fmaxf(m_true[reg], __shfl_xor(m_true[reg], o));
  if (h == 0 && l15 == 0) {
#pragma unroll
    for (int reg = 0; reg < 4; ++reg)
      SmaxOut[b * TP + i0 + pr * 16 + g * 4 + reg] = m_true[reg];
  }

  // ---- epilogue: normalize, park U_att (f16) in LDS, coalesced G writes ----
  float inv_l[4];
#pragma unroll
  for (int reg = 0; reg < 4; ++reg) inv_l[reg] = 1.0f / Lacc[reg];
  __syncthreads();
#pragma unroll
  for (int n = 0; n < 8; ++n)
#pragma unroll
    for (int reg = 0; reg < 4; ++reg)
      Uatt[pr * 16 + g * 4 + reg][h * 128 + n * 16 + l15] =
          (_Float16)(Oacc[n][reg] * inv_l[reg]);
  __syncthreads();

  const int* pmb = mp + b * TP + i0;
#pragma unroll
  for (int it = 0; it < 8; ++it) {
    int idx4 = it * 512 + tid;
    int r = idx4 >> 6, c = (idx4 & 63) * 4;
    float pm = (float)pmb[r];
    f32x4 hv = *(const f32x4*)&H[((size_t)b * TP + i0 + r) * D2_ + c];
    hv *= pm;
    f16x4 u4 = *(const f16x4*)&Uatt[r][c];
    f32x4 u; u.x = (float)u4[0]; u.y = (float)u4[1]; u.z = (float)u4[2]; u.w = (float)u4[3];
    size_t ro = ((size_t)b * TP + i0 + r) * (4 * D2_);
    *(f32x4*)&G[ro + c] = hv;
    f32x4 up = u * pm;
    *(f32x4*)&G[ro + D2_ + c] = up;
    f32x4 hu; hu.x = hv.x * u.x; hu.y = hv.y * u.y; hu.z = hv.z * u.z; hu.w = hv.w * u.w;
    *(f32x4*)&G[ro + 2 * D2_ + c] = hu;
  }
}

// ---------------- kernel 3a: per-batch max & sum-exp over Smax ----------------
__global__ __launch_bounds__(256) void k_smax_reduce(const float* __restrict__ Smax,
    const int* __restrict__ mp, float* __restrict__ Mb, float* __restrict__ Lb) {
  int b = blockIdx.x;
  int tid = threadIdx.x;
  const float* S = Smax + b * TP;
  const int* pm = mp + b * TP;
  __shared__ float redm[4], reds[4];
  float mx = -1e30f;
  for (int i = tid; i < TP; i += 256) mx = fmaxf(mx, S[i]);
#pragma unroll
  for (int o = 32; o; o >>= 1) mx = fmaxf(mx, __shfl_down(mx, o));
  if ((tid & 63) == 0) redm[tid >> 6] = mx;
  __syncthreads();
  mx = fmaxf(fmaxf(redm[0], redm[1]), fmaxf(redm[2], redm[3]));
  float s = 0.f;
  for (int i = tid; i < TP; i += 256) s += pm[i] ? __expf(S[i] - mx) : 0.f;
#pragma unroll
  for (int o = 32; o; o >>= 1) s += __shfl_down(s, o);
  if ((tid & 63) == 0) reds[tid >> 6] = s;
  __syncthreads();
  if (tid == 0) { Mb[b] = mx; Lb[b] = reds[0] + reds[1] + reds[2] + reds[3]; }
}

// ---------------- kernel 3b: partial h_att (deterministic) ----------------
__global__ __launch_bounds__(256) void k_hatt(const float* __restrict__ H,
    const float* __restrict__ Smax, const int* __restrict__ mp,
    const float* __restrict__ Mb, const float* __restrict__ Lb,
    float* __restrict__ partial) {
  int b = blockIdx.y;
  int chunk = blockIdx.x;
  int c = threadIdx.x;
  float mx = Mb[b];
  float inv = 1.0f / Lb[b];
  float acc = 0.f;
  int i0 = chunk * 128;
  for (int ii = 0; ii < 128; ++ii) {
    int i = i0 + ii;
    float sm = Smax[b * TP + i];
    float wgt = mp[b * TP + i] ? __expf(sm - mx) * inv : 0.f;
    acc += wgt * H[((size_t)b * TP + i) * D2_ + c];
  }
  partial[((size_t)b * 32 + chunk) * D2_ + c] = acc;
}

// ---------------- kernel 3c: sum partials -> h_att ----------------
__global__ __launch_bounds__(256) void k_hatt_sum(const float* __restrict__ partial,
                                                  float* __restrict__ hatt) {
  int b = blockIdx.x;
  int c = threadIdx.x;
  float s = 0.f;
#pragma unroll
  for (int k = 0; k < 32; ++k) s += partial[((size_t)b * 32 + k) * D2_ + c];
  hatt[b * D2_ + c] = s;
}

// ---------------- kernel 4: G slice 3 = Hm * h_att ----------------
__global__ __launch_bounds__(256) void k_g3(const float* __restrict__ H,
    const int* __restrict__ mp, const float* __restrict__ hatt,
    float* __restrict__ G) {
  const int total = B_ * TP * (D2_ / 4);
  for (int idx = blockIdx.x * 256 + threadIdx.x; idx < total; idx += gridDim.x * 256) {
    int c4 = idx & 63;
    int i = (idx >> 6) & (TP - 1);
    int b = idx >> 18;
    float pm = (float)mp[b * TP + i];
    f32x4 h = *(const f32x4*)&H[((size_t)b * TP + i) * D2_ + c4 * 4];
    f32x4 ha = *(const f32x4*)&hatt[b * D2_ + c4 * 4];
    f32x4 o;
    o.x = h.x * pm * ha.x; o.y = h.y * pm * ha.y;
    o.z = h.z * pm * ha.z; o.w = h.w * pm * ha.w;
    *(f32x4*)&G[((size_t)b * TP + i) * (4 * D2_) + 3 * D2_ + c4 * 4] = o;
  }
}

extern "C" void kernel_launch(void* const* d_in, const int* in_sizes, int n_in,
                              void* d_out, int out_size, void* d_ws, size_t ws_size,
                              hipStream_t stream) {
  const float* H  = (const float*)d_in[0];
  const float* U  = (const float*)d_in[1];
  const float* w  = (const float*)d_in[2];
  const int*   mp = (const int*)d_in[3];
  const int*   mq = (const int*)d_in[4];
  float* G = (float*)d_out;

  float* ws      = (float*)d_ws;
  float* udot    = ws;                       // 8192
  float* Smax    = udot + B_ * TQ;           // 65536
  float* Mb      = Smax + B_ * TP;           // 16
  float* Lb      = Mb + B_;                  // 16
  float* hatt    = Lb + B_;                  // 4096
  float* partial = hatt + B_ * D2_;          // 131072

  k_prep<<<dim3(NJT, B_), 256, 0, stream>>>(U, w, mq, G, udot);
  k_main<<<dim3(TP / TI, B_), 512, 0, stream>>>(H, w, mp, mq, udot, Smax, G);
  k_smax_reduce<<<dim3(B_), 256, 0, stream>>>(Smax, mp, Mb, Lb);
  k_hatt<<<dim3(32, B_), 256, 0, stream>>>(H, Smax, mp, Mb, Lb, partial);
  k_hatt_sum<<<dim3(B_), 256, 0, stream>>>(partial, hatt);
  k_g3<<<dim3(2048), 256, 0, stream>>>(H, mp, hatt, G);
}

// Round 5
// 226.960 us; speedup vs baseline: 1.3473x; 1.3473x over previous
//
#include <hip/hip_runtime.h>
#include <hip/hip_bf16.h>
#include <cstdint>

#define B_  16
#define TP  4096
#define TQ  512
#define D2_ 256
#define TI 64
#define TJ 32
#define NJT (TQ / TJ)   // 16

typedef _Float16 f16x8 __attribute__((ext_vector_type(8)));
typedef _Float16 f16x4 __attribute__((ext_vector_type(4)));
typedef float    f32x4 __attribute__((ext_vector_type(4)));

// ---- fragment blob stash: G slice-3 (last 1KB of each 4KB row) of rows 0..8191 ----
__device__ __forceinline__ _Float16* frag_wptr(float* G, int b, int jt, int f, int lane) {
  return (_Float16*)G + ((size_t)((b * NJT + jt) * 32 + f)) * 2048 + 1536 + lane * 8;
}

// ---------------- kernel 0: build f16 B-fragments + udot ----------------
__global__ __launch_bounds__(256) void k_prep(const float* __restrict__ U,
                                              const float* __restrict__ w,
                                              const int* __restrict__ mq,
                                              float* __restrict__ G,
                                              float* __restrict__ udot) {
  __shared__ _Float16 T[TJ][264];
  const int b = blockIdx.y, jt = blockIdx.x;
  const int tid = threadIdx.x, lane = tid & 63, wv = tid >> 6;
  const int l15 = lane & 15, g = lane >> 4;

#pragma unroll
  for (int it = 0; it < 8; ++it) {
    int chunk = it * 256 + tid;
    int r = chunk >> 6, c = (chunk & 63) * 4;
    int row = b * TQ + jt * TJ + r;
    float qmv = (float)mq[row];
    f32x4 u = *(const f32x4*)&U[(size_t)row * D2_ + c];
    f16x4 v;
    v[0] = (_Float16)(u.x * qmv); v[1] = (_Float16)(u.y * qmv);
    v[2] = (_Float16)(u.z * qmv); v[3] = (_Float16)(u.w * qmv);
    *(f16x4*)&T[r][c] = v;
  }
  __syncthreads();

  {
    int r = tid >> 3, s = tid & 7;
    float p = 0.f;
#pragma unroll
    for (int e = 0; e < 32; ++e) p += (float)T[r][s * 32 + e] * w[D2_ + s * 32 + e];
    p += __shfl_xor(p, 1); p += __shfl_xor(p, 2); p += __shfl_xor(p, 4);
    if (s == 0) udot[b * TQ + jt * TJ + r] = p;
  }

#pragma unroll
  for (int q = 0; q < 8; ++q) {
    int f = wv * 8 + q;
    f16x8 v;
    if (f < 16) {
      int t = f >> 3, ks = f & 7;
      v = *(const f16x8*)&T[t * 16 + l15][ks * 32 + g * 8];
    } else {
      int n = f - 16;
#pragma unroll
      for (int e = 0; e < 8; ++e) v[e] = T[g * 8 + e][n * 16 + l15];
    }
    *(f16x8*)frag_wptr(G, b, jt, f, lane) = v;
  }
}

// ---------------- kernel 1: flash S/softmax/PV; LDS-shared frags, dbuf pipeline ----------------
__global__ __launch_bounds__(512, 4) void k_main(
    const float* __restrict__ H, const float* __restrict__ w,
    const int* __restrict__ mp, const int* __restrict__ mq,
    const float* __restrict__ udot,
    float* __restrict__ SmaxOut, float* __restrict__ G) {

  __shared__ _Float16 Fbuf[2][32][512];    // 65536 B: 32 frags x (64 lanes x 8 f16)
  __shared__ _Float16 P[8][16][40];        // 10240 B per-wave P tiles
  _Float16 (*Uatt)[264] = (_Float16(*)[264])&Fbuf[0][0][0];  // epilogue reuse (33792 B)

  const int b = blockIdx.y, i0 = blockIdx.x * TI;
  const int tid = threadIdx.x, lane = tid & 63, wv = tid >> 6;
  const int l15 = lane & 15, g = lane >> 4;
  const int pr = wv >> 1;        // pair: rows pr*16..+15
  const int h  = wv & 1;         // c-half for PV

  const _Float16* Gf = (const _Float16*)G;

  // ---- issue jt=0 staging loads (latency hides under afr compute) ----
  f16x8 st[4];
  {
    const _Float16* fb0 = Gf + ((size_t)(b * NJT) * 32) * 2048 + 1536 + lane * 8;
#pragma unroll
    for (int q = 0; q < 4; ++q)
      st[q] = *(const f16x8*)(fb0 + (size_t)(wv * 4 + q) * 2048);
  }

  // ---- prologue: every wave computes its A-fragments (Hm*w_hu) + hdot ----
  const int rowg = i0 + pr * 16 + l15;
  const float* Hrow = H + ((size_t)b * TP + rowg) * D2_;
  const float pmr = (float)mp[b * TP + rowg];
  f16x8 afr[8];
  float hp = 0.f;
#pragma unroll
  for (int ks = 0; ks < 8; ++ks) {
    int c0 = ks * 32 + g * 8;
    f32x4 h0 = *(const f32x4*)&Hrow[c0];
    f32x4 h1 = *(const f32x4*)&Hrow[c0 + 4];
    f32x4 wh0 = *(const f32x4*)&w[c0];
    f32x4 wh1 = *(const f32x4*)&w[c0 + 4];
    f32x4 wu0 = *(const f32x4*)&w[2 * D2_ + c0];
    f32x4 wu1 = *(const f32x4*)&w[2 * D2_ + c0 + 4];
    h0 *= pmr; h1 *= pmr;
    f16x8 a;
    a[0] = (_Float16)(h0.x * wu0.x); a[1] = (_Float16)(h0.y * wu0.y);
    a[2] = (_Float16)(h0.z * wu0.z); a[3] = (_Float16)(h0.w * wu0.w);
    a[4] = (_Float16)(h1.x * wu1.x); a[5] = (_Float16)(h1.y * wu1.y);
    a[6] = (_Float16)(h1.z * wu1.z); a[7] = (_Float16)(h1.w * wu1.w);
    afr[ks] = a;
    hp += h0.x * wh0.x + h0.y * wh0.y + h0.z * wh0.z + h0.w * wh0.w
        + h1.x * wh1.x + h1.y * wh1.y + h1.z * wh1.z + h1.w * wh1.w;
  }
  hp += __shfl_xor(hp, 16);
  hp += __shfl_xor(hp, 32);      // all lanes: hdot of row (pr*16 + l15)
  float hd[4];
#pragma unroll
  for (int reg = 0; reg < 4; ++reg) hd[reg] = __shfl(hp, g * 4 + reg);

  // ---- commit jt=0 staging ----
#pragma unroll
  for (int q = 0; q < 4; ++q)
    *(f16x8*)&Fbuf[0][wv * 4 + q][lane * 8] = st[q];
  __syncthreads();

  f32x4 Oacc[8];
#pragma unroll
  for (int n = 0; n < 8; ++n) Oacc[n] = {0.f, 0.f, 0.f, 0.f};
  f32x4 Lacc = {0.f, 0.f, 0.f, 0.f};
  float m_r[4]    = {-1e30f, -1e30f, -1e30f, -1e30f};
  float m_true[4] = {-1e30f, -1e30f, -1e30f, -1e30f};

  f16x8 ones;
#pragma unroll
  for (int e = 0; e < 8; ++e) ones[e] = (_Float16)1.0f;

  int cur = 0;
  for (int jt = 0; jt < NJT; ++jt) {
    // ---- issue next-tile staging loads early ----
    if (jt + 1 < NJT) {
      const _Float16* fbn = Gf + ((size_t)((b * NJT + jt + 1) * 32)) * 2048 + 1536 + lane * 8;
#pragma unroll
      for (int q = 0; q < 4; ++q)
        st[q] = *(const f16x8*)(fbn + (size_t)(wv * 4 + q) * 2048);
    }
    float ud[2], qv[2];
#pragma unroll
    for (int t = 0; t < 2; ++t) {
      ud[t] = udot[b * TQ + jt * TJ + t * 16 + l15];
      qv[t] = (float)mq[b * TQ + jt * TJ + t * 16 + l15];
    }

    // ---- S: 16 rows x 32 cols from LDS frags ----
    f32x4 Sacc[2];
    Sacc[0] = {0.f, 0.f, 0.f, 0.f}; Sacc[1] = {0.f, 0.f, 0.f, 0.f};
#pragma unroll
    for (int ks = 0; ks < 8; ++ks) {
      f16x8 b0 = *(const f16x8*)&Fbuf[cur][ks][lane * 8];
      f16x8 b1 = *(const f16x8*)&Fbuf[cur][8 + ks][lane * 8];
      Sacc[0] = __builtin_amdgcn_mfma_f32_16x16x32_f16(afr[ks], b0, Sacc[0], 0, 0, 0);
      Sacc[1] = __builtin_amdgcn_mfma_f32_16x16x32_f16(afr[ks], b1, Sacc[1], 0, 0, 0);
    }

    // ---- bias + online softmax (branch-free, unconditional rescale) ----
    float tmax[4];
#pragma unroll
    for (int reg = 0; reg < 4; ++reg) {
      float v0 = Sacc[0][reg] + hd[reg] + ud[0];
      float v1 = Sacc[1][reg] + hd[reg] + ud[1];
      Sacc[0][reg] = v0; Sacc[1][reg] = v1;
      tmax[reg] = fmaxf(v0, v1);
      m_true[reg] = fmaxf(m_true[reg], tmax[reg]);
    }
#pragma unroll
    for (int o = 1; o < 16; o <<= 1)
#pragma unroll
      for (int reg = 0; reg < 4; ++reg)
        tmax[reg] = fmaxf(tmax[reg], __shfl_xor(tmax[reg], o));

#pragma unroll
    for (int reg = 0; reg < 4; ++reg) {
      float mn = fmaxf(m_r[reg], tmax[reg]);
      float sc = __expf(m_r[reg] - mn);
      m_r[reg] = mn;
      Lacc[reg] *= sc;
#pragma unroll
      for (int n = 0; n < 8; ++n) Oacc[n][reg] *= sc;
    }

#pragma unroll
    for (int t = 0; t < 2; ++t)
#pragma unroll
      for (int reg = 0; reg < 4; ++reg) {
        float p = qv[t] * __expf(Sacc[t][reg] - m_r[reg]);
        P[wv][g * 4 + reg][t * 16 + l15] = (_Float16)p;
      }

    // ---- PV + row-sum-via-MFMA, frags from LDS ----
    f16x8 pf = *(const f16x8*)&P[wv][l15][g * 8];
    Lacc = __builtin_amdgcn_mfma_f32_16x16x32_f16(pf, ones, Lacc, 0, 0, 0);
#pragma unroll
    for (int n = 0; n < 8; ++n) {
      f16x8 uf = *(const f16x8*)&Fbuf[cur][16 + h * 8 + n][lane * 8];
      Oacc[n] = __builtin_amdgcn_mfma_f32_16x16x32_f16(pf, uf, Oacc[n], 0, 0, 0);
    }

    // ---- commit staged tile into other buffer, flip ----
    if (jt + 1 < NJT) {
#pragma unroll
      for (int q = 0; q < 4; ++q)
        *(f16x8*)&Fbuf[cur ^ 1][wv * 4 + q][lane * 8] = st[q];
    }
    __syncthreads();
    cur ^= 1;
  }

  // ---- final true-max reduce + Smax out ----
#pragma unroll
  for (int o = 1; o < 16; o <<= 1)
#pragma unroll
    for (int reg = 0; reg < 4; ++reg)
      m_true[reg] = fmaxf(m_true[reg], __shfl_xor(m_true[reg], o));
  if (h == 0 && l15 == 0) {
#pragma unroll
    for (int reg = 0; reg < 4; ++reg)
      SmaxOut[b * TP + i0 + pr * 16 + g * 4 + reg] = m_true[reg];
  }

  // ---- epilogue: normalize, park U_att (f16) in LDS, coalesced G writes ----
  float inv_l[4];
#pragma unroll
  for (int reg = 0; reg < 4; ++reg) inv_l[reg] = 1.0f / Lacc[reg];
  __syncthreads();
#pragma unroll
  for (int n = 0; n < 8; ++n)
#pragma unroll
    for (int reg = 0; reg < 4; ++reg)
      Uatt[pr * 16 + g * 4 + reg][h * 128 + n * 16 + l15] =
          (_Float16)(Oacc[n][reg] * inv_l[reg]);
  __syncthreads();

  const int* pmb = mp + b * TP + i0;
#pragma unroll
  for (int it = 0; it < 8; ++it) {
    int idx4 = it * 512 + tid;
    int r = idx4 >> 6, c = (idx4 & 63) * 4;
    float pm = (float)pmb[r];
    f32x4 hv = *(const f32x4*)&H[((size_t)b * TP + i0 + r) * D2_ + c];
    hv *= pm;
    f16x4 u4 = *(const f16x4*)&Uatt[r][c];
    f32x4 u; u.x = (float)u4[0]; u.y = (float)u4[1]; u.z = (float)u4[2]; u.w = (float)u4[3];
    size_t ro = ((size_t)b * TP + i0 + r) * (4 * D2_);
    *(f32x4*)&G[ro + c] = hv;
    f32x4 up = u * pm;
    *(f32x4*)&G[ro + D2_ + c] = up;
    f32x4 hu; hu.x = hv.x * u.x; hu.y = hv.y * u.y; hu.z = hv.z * u.z; hu.w = hv.w * u.w;
    *(f32x4*)&G[ro + 2 * D2_ + c] = hu;
  }
}

// ---------------- kernel 3a: per-batch max & sum-exp over Smax ----------------
__global__ __launch_bounds__(256) void k_smax_reduce(const float* __restrict__ Smax,
    const int* __restrict__ mp, float* __restrict__ Mb, float* __restrict__ Lb) {
  int b = blockIdx.x;
  int tid = threadIdx.x;
  const float* S = Smax + b * TP;
  const int* pm = mp + b * TP;
  __shared__ float redm[4], reds[4];
  float mx = -1e30f;
  for (int i = tid; i < TP; i += 256) mx = fmaxf(mx, S[i]);
#pragma unroll
  for (int o = 32; o; o >>= 1) mx = fmaxf(mx, __shfl_down(mx, o));
  if ((tid & 63) == 0) redm[tid >> 6] = mx;
  __syncthreads();
  mx = fmaxf(fmaxf(redm[0], redm[1]), fmaxf(redm[2], redm[3]));
  float s = 0.f;
  for (int i = tid; i < TP; i += 256) s += pm[i] ? __expf(S[i] - mx) : 0.f;
#pragma unroll
  for (int o = 32; o; o >>= 1) s += __shfl_down(s, o);
  if ((tid & 63) == 0) reds[tid >> 6] = s;
  __syncthreads();
  if (tid == 0) { Mb[b] = mx; Lb[b] = reds[0] + reds[1] + reds[2] + reds[3]; }
}

// ---------------- kernel 3b: partial h_att (deterministic) ----------------
__global__ __launch_bounds__(256) void k_hatt(const float* __restrict__ H,
    const float* __restrict__ Smax, const int* __restrict__ mp,
    const float* __restrict__ Mb, const float* __restrict__ Lb,
    float* __restrict__ partial) {
  int b = blockIdx.y;
  int chunk = blockIdx.x;
  int c = threadIdx.x;
  float mx = Mb[b];
  float inv = 1.0f / Lb[b];
  float acc = 0.f;
  int i0 = chunk * 128;
  for (int ii = 0; ii < 128; ++ii) {
    int i = i0 + ii;
    float sm = Smax[b * TP + i];
    float wgt = mp[b * TP + i] ? __expf(sm - mx) * inv : 0.f;
    acc += wgt * H[((size_t)b * TP + i) * D2_ + c];
  }
  partial[((size_t)b * 32 + chunk) * D2_ + c] = acc;
}

// ---------------- kernel 3c: sum partials -> h_att ----------------
__global__ __launch_bounds__(256) void k_hatt_sum(const float* __restrict__ partial,
                                                  float* __restrict__ hatt) {
  int b = blockIdx.x;
  int c = threadIdx.x;
  float s = 0.f;
#pragma unroll
  for (int k = 0; k < 32; ++k) s += partial[((size_t)b * 32 + k) * D2_ + c];
  hatt[b * D2_ + c] = s;
}

// ---------------- kernel 4: G slice 3 = Hm * h_att ----------------
__global__ __launch_bounds__(256) void k_g3(const float* __restrict__ H,
    const int* __restrict__ mp, const float* __restrict__ hatt,
    float* __restrict__ G) {
  const int total = B_ * TP * (D2_ / 4);
  for (int idx = blockIdx.x * 256 + threadIdx.x; idx < total; idx += gridDim.x * 256) {
    int c4 = idx & 63;
    int i = (idx >> 6) & (TP - 1);
    int b = idx >> 18;
    float pm = (float)mp[b * TP + i];
    f32x4 h = *(const f32x4*)&H[((size_t)b * TP + i) * D2_ + c4 * 4];
    f32x4 ha = *(const f32x4*)&hatt[b * D2_ + c4 * 4];
    f32x4 o;
    o.x = h.x * pm * ha.x; o.y = h.y * pm * ha.y;
    o.z = h.z * pm * ha.z; o.w = h.w * pm * ha.w;
    *(f32x4*)&G[((size_t)b * TP + i) * (4 * D2_) + 3 * D2_ + c4 * 4] = o;
  }
}

extern "C" void kernel_launch(void* const* d_in, const int* in_sizes, int n_in,
                              void* d_out, int out_size, void* d_ws, size_t ws_size,
                              hipStream_t stream) {
  const float* H  = (const float*)d_in[0];
  const float* U  = (const float*)d_in[1];
  const float* w  = (const float*)d_in[2];
  const int*   mp = (const int*)d_in[3];
  const int*   mq = (const int*)d_in[4];
  float* G = (float*)d_out;

  float* ws      = (float*)d_ws;
  float* udot    = ws;                       // 8192
  float* Smax    = udot + B_ * TQ;           // 65536
  float* Mb      = Smax + B_ * TP;           // 16
  float* Lb      = Mb + B_;                  // 16
  float* hatt    = Lb + B_;                  // 4096
  float* partial = hatt + B_ * D2_;          // 131072

  k_prep<<<dim3(NJT, B_), 256, 0, stream>>>(U, w, mq, G, udot);
  k_main<<<dim3(TP / TI, B_), 512, 0, stream>>>(H, w, mp, mq, udot, Smax, G);
  k_smax_reduce<<<dim3(B_), 256, 0, stream>>>(Smax, mp, Mb, Lb);
  k_hatt<<<dim3(32, B_), 256, 0, stream>>>(H, Smax, mp, Mb, Lb, partial);
  k_hatt_sum<<<dim3(B_), 256, 0, stream>>>(partial, hatt);
  k_g3<<<dim3(2048), 256, 0, stream>>>(H, mp, hatt, G);
}

// Round 6
// 214.759 us; speedup vs baseline: 1.4238x; 1.0568x over previous
//
#include <hip/hip_runtime.h>
#include <hip/hip_bf16.h>
#include <cstdint>

#define B_  16
#define TP  4096
#define TQ  512
#define D2_ 256
#define TI 64
#define TJ 32
#define NJT (TQ / TJ)   // 16
#define NFRAG 35        // 16 S-frags + 2 ext + 16 PV + 1 qm

typedef _Float16 f16x8 __attribute__((ext_vector_type(8)));
typedef _Float16 f16x4 __attribute__((ext_vector_type(4)));
typedef float    f32x4 __attribute__((ext_vector_type(4)));

// ---- fragment blob stash: slice-3 (last 1KB) of G rows 0..8959 ----
// frag (b,jt,f) = G row (b*NJT+jt)*35 + f, bytes [3072,4096). k_main writes only
// slices 0..2 of G rows; k_g3 (after k_main) overwrites slice 3 with output.
__device__ __forceinline__ _Float16* frag_ptr(float* G, int b, int jt, int f, int lane) {
  return (_Float16*)G + ((size_t)((b * NJT + jt) * NFRAG + f)) * 2048 + 1536 + lane * 8;
}

// ---------------- kernel 0: build f16 fragments (S-A, ext, PV-B, qm) ----------------
__global__ __launch_bounds__(256) void k_prep(const float* __restrict__ U,
                                              const float* __restrict__ w,
                                              const int* __restrict__ mq,
                                              float* __restrict__ G) {
  __shared__ _Float16 T[TJ][264];
  __shared__ float uds[TJ];
  __shared__ float qs[TJ];
  const int b = blockIdx.y, jt = blockIdx.x;
  const int tid = threadIdx.x, lane = tid & 63, wv = tid >> 6;
  const int l15 = lane & 15, g = lane >> 4;

  if (tid < TJ) qs[tid] = (float)mq[b * TQ + jt * TJ + tid];

  // stage Um tile (32 x 256) as f16
#pragma unroll
  for (int it = 0; it < 8; ++it) {
    int chunk = it * 256 + tid;
    int r = chunk >> 6, c = (chunk & 63) * 4;
    int row = b * TQ + jt * TJ + r;
    float qmv = (float)mq[row];
    f32x4 u = *(const f32x4*)&U[(size_t)row * D2_ + c];
    f16x4 v;
    v[0] = (_Float16)(u.x * qmv); v[1] = (_Float16)(u.y * qmv);
    v[2] = (_Float16)(u.z * qmv); v[3] = (_Float16)(u.w * qmv);
    *(f16x4*)&T[r][c] = v;
  }
  __syncthreads();

  // udot per row (from masked f16 tile)
  {
    int r = tid >> 3, s = tid & 7;
    float p = 0.f;
#pragma unroll
    for (int e = 0; e < 32; ++e) p += (float)T[r][s * 32 + e] * w[D2_ + s * 32 + e];
    p += __shfl_xor(p, 1); p += __shfl_xor(p, 2); p += __shfl_xor(p, 4);
    if (s == 0) uds[r] = p;
  }
  __syncthreads();

  // emit fragments: 4 waves, f = q*4 + wv
#pragma unroll
  for (int q = 0; q < 9; ++q) {
    int f = q * 4 + wv;
    if (f >= NFRAG) continue;
    f16x8 v;
#pragma unroll
    for (int e = 0; e < 8; ++e) v[e] = (_Float16)0.0f;
    if (f < 16) {
      // S A-frag (t,ks): A[j = t*16+l15][c = ks*32+g*8+e]
      int t = f >> 3, ks = f & 7;
      v = *(const f16x8*)&T[t * 16 + l15][ks * 32 + g * 8];
    } else if (f < 18) {
      // ext A-frag: [ud_j, 1, 0...] in k-group g==0
      int t = f - 16;
      if (g == 0) { v[0] = (_Float16)uds[t * 16 + l15]; v[1] = (_Float16)1.0f; }
    } else if (f < 34) {
      // PV B-frag (n): B[j = g*8+e][c = n*16+l15]
      int n = f - 18;
#pragma unroll
      for (int e = 0; e < 8; ++e) v[e] = T[g * 8 + e][n * 16 + l15];
    } else {
      // qm-frag: B[j = g*8+e][*] = qm_j
#pragma unroll
      for (int e = 0; e < 8; ++e) v[e] = (_Float16)qs[g * 8 + e];
    }
    *(f16x8*)frag_ptr(G, b, jt, f, lane) = v;
  }
}

// ---------------- kernel 1: transposed-S flash, folded bias, deferred rescale ----------------
__global__ __launch_bounds__(512, 4) void k_main(
    const float* __restrict__ H, const float* __restrict__ w,
    const int* __restrict__ mp,
    float* __restrict__ SmaxOut, float* __restrict__ G) {

  __shared__ _Float16 Fbuf[2][NFRAG][512];   // 71680 B (frag f: 64 lanes x 16B)
  __shared__ _Float16 Plds[8][16][40];       // 10240 B per-wave P relayout
  _Float16 (*Uatt)[264] = (_Float16(*)[264])&Fbuf[0][0][0];   // epilogue reuse

  const int b = blockIdx.y, i0 = blockIdx.x * TI;
  const int tid = threadIdx.x, lane = tid & 63, wv = tid >> 6;
  const int l15 = lane & 15, g = lane >> 4;
  const int pr = wv >> 1;        // pair: rows i0 + pr*16 .. +15
  const int h  = wv & 1;         // c-half for PV

  const _Float16* Gf = (const _Float16*)G;
  auto tilebase = [&](int jt) {
    return Gf + ((size_t)((b * NJT + jt) * NFRAG)) * 2048 + 1536 + (size_t)lane * 8;
  };

  // ---- issue tile-0 staging loads ----
  f16x8 st[5];
  {
    const _Float16* fb = tilebase(0);
#pragma unroll
    for (int q = 0; q < 5; ++q) {
      int f = q * 8 + wv;
      if (f < NFRAG) st[q] = *(const f16x8*)(fb + (size_t)f * 2048);
    }
  }

  // ---- prologue: h-frags (B-operand: col=l15=i, k=c) + hdot ----
  const int rowg = i0 + pr * 16 + l15;
  const float* Hrow = H + ((size_t)b * TP + rowg) * D2_;
  const float pmr = (float)mp[b * TP + rowg];
  f16x8 afr[8];
  float hp = 0.f;
#pragma unroll
  for (int ks = 0; ks < 8; ++ks) {
    int c0 = ks * 32 + g * 8;
    f32x4 h0 = *(const f32x4*)&Hrow[c0];
    f32x4 h1 = *(const f32x4*)&Hrow[c0 + 4];
    f32x4 wh0 = *(const f32x4*)&w[c0];
    f32x4 wh1 = *(const f32x4*)&w[c0 + 4];
    f32x4 wu0 = *(const f32x4*)&w[2 * D2_ + c0];
    f32x4 wu1 = *(const f32x4*)&w[2 * D2_ + c0 + 4];
    h0 *= pmr; h1 *= pmr;
    f16x8 a;
    a[0] = (_Float16)(h0.x * wu0.x); a[1] = (_Float16)(h0.y * wu0.y);
    a[2] = (_Float16)(h0.z * wu0.z); a[3] = (_Float16)(h0.w * wu0.w);
    a[4] = (_Float16)(h1.x * wu1.x); a[5] = (_Float16)(h1.y * wu1.y);
    a[6] = (_Float16)(h1.z * wu1.z); a[7] = (_Float16)(h1.w * wu1.w);
    afr[ks] = a;
    hp += h0.x * wh0.x + h0.y * wh0.y + h0.z * wh0.z + h0.w * wh0.w
        + h1.x * wh1.x + h1.y * wh1.y + h1.z * wh1.z + h1.w * wh1.w;
  }
  hp += __shfl_xor(hp, 16);
  hp += __shfl_xor(hp, 32);              // hdot for i = l15 of this pair
  f16x8 bext;
#pragma unroll
  for (int e = 0; e < 8; ++e) bext[e] = (_Float16)0.0f;
  if (g == 0) { bext[0] = (_Float16)1.0f; bext[1] = (_Float16)hp; }

  // ---- commit tile 0 ----
#pragma unroll
  for (int q = 0; q < 5; ++q) {
    int f = q * 8 + wv;
    if (f < NFRAG) *(f16x8*)&Fbuf[0][f][lane * 8] = st[q];
  }
  __syncthreads();

  f32x4 Oacc[8];
#pragma unroll
  for (int n = 0; n < 8; ++n) Oacc[n] = {0.f, 0.f, 0.f, 0.f};
  f32x4 Lacc = {0.f, 0.f, 0.f, 0.f};
  float m_run  = -1e30f;
  float m_true = -1e30f;

  int cur = 0;
  for (int jt = 0; jt < NJT; ++jt) {
    // ---- issue next-tile staging loads ----
    if (jt + 1 < NJT) {
      const _Float16* fb = tilebase(jt + 1);
#pragma unroll
      for (int q = 0; q < 5; ++q) {
        int f = q * 8 + wv;
        if (f < NFRAG) st[q] = *(const f16x8*)(fb + (size_t)f * 2048);
      }
    }

    // ---- S^T: mfma(A=Um-frag, B=h-frag) -> C[j = g*4+reg][i = l15] ----
    f32x4 S0 = {0.f, 0.f, 0.f, 0.f}, S1 = {0.f, 0.f, 0.f, 0.f};
#pragma unroll
    for (int ks = 0; ks < 8; ++ks) {
      f16x8 a0 = *(const f16x8*)&Fbuf[cur][ks][lane * 8];
      f16x8 a1 = *(const f16x8*)&Fbuf[cur][8 + ks][lane * 8];
      S0 = __builtin_amdgcn_mfma_f32_16x16x32_f16(a0, afr[ks], S0, 0, 0, 0);
      S1 = __builtin_amdgcn_mfma_f32_16x16x32_f16(a1, afr[ks], S1, 0, 0, 0);
    }
    {
      f16x8 ax0 = *(const f16x8*)&Fbuf[cur][16][lane * 8];
      f16x8 ax1 = *(const f16x8*)&Fbuf[cur][17][lane * 8];
      S0 = __builtin_amdgcn_mfma_f32_16x16x32_f16(ax0, bext, S0, 0, 0, 0);
      S1 = __builtin_amdgcn_mfma_f32_16x16x32_f16(ax1, bext, S1, 0, 0, 0);
    }

    // ---- softmax (lane-local in i=l15), deferred rescale ----
    float lmax = fmaxf(fmaxf(fmaxf(S0[0], S0[1]), fmaxf(S0[2], S0[3])),
                       fmaxf(fmaxf(S1[0], S1[1]), fmaxf(S1[2], S1[3])));
    lmax = fmaxf(lmax, __shfl_xor(lmax, 16));
    lmax = fmaxf(lmax, __shfl_xor(lmax, 32));   // row max over all 32 j
    m_true = fmaxf(m_true, lmax);
    if (__any(lmax - m_run > 8.0f)) {
      float mn = fmaxf(m_run, lmax);
      float sc = __expf(m_run - mn);
      m_run = mn;
#pragma unroll
      for (int reg = 0; reg < 4; ++reg) {
        float scr = __shfl(sc, g * 4 + reg);   // sc for i = g*4+reg
        Lacc[reg] *= scr;
#pragma unroll
        for (int n = 0; n < 8; ++n) Oacc[n][reg] *= scr;
      }
    }

    f16x4 ph0, ph1;
#pragma unroll
    for (int reg = 0; reg < 4; ++reg) {
      ph0[reg] = (_Float16)__expf(S0[reg] - m_run);
      ph1[reg] = (_Float16)__expf(S1[reg] - m_run);
    }
    // relayout P: [i=l15][j] pitch 40 f16; write j-runs of 4, read j = g*8..g*8+7
    *(f16x4*)&Plds[wv][l15][g * 4]      = ph0;
    *(f16x4*)&Plds[wv][l15][16 + g * 4] = ph1;
    f16x8 pa = *(const f16x8*)&Plds[wv][l15][g * 8];

    // ---- PV (K=32) + l via qm-frag ----
    {
      f16x8 qmf = *(const f16x8*)&Fbuf[cur][34][lane * 8];
      Lacc = __builtin_amdgcn_mfma_f32_16x16x32_f16(pa, qmf, Lacc, 0, 0, 0);
    }
#pragma unroll
    for (int n = 0; n < 8; ++n) {
      f16x8 bu = *(const f16x8*)&Fbuf[cur][18 + h * 8 + n][lane * 8];
      Oacc[n] = __builtin_amdgcn_mfma_f32_16x16x32_f16(pa, bu, Oacc[n], 0, 0, 0);
    }

    // ---- commit staged tile, flip ----
    if (jt + 1 < NJT) {
#pragma unroll
      for (int q = 0; q < 5; ++q) {
        int f = q * 8 + wv;
        if (f < NFRAG) *(f16x8*)&Fbuf[cur ^ 1][f][lane * 8] = st[q];
      }
    }
    __syncthreads();
    cur ^= 1;
  }

  // ---- Smax out (raw row max, row-uniform in lanes l15) ----
  if (h == 0 && lane < 16)
    SmaxOut[b * TP + i0 + pr * 16 + lane] = m_true;

  // ---- epilogue: normalize, park U_att (f16) in LDS, coalesced G writes ----
  float inv_l[4];
#pragma unroll
  for (int reg = 0; reg < 4; ++reg) inv_l[reg] = 1.0f / Lacc[reg];
#pragma unroll
  for (int n = 0; n < 8; ++n)
#pragma unroll
    for (int reg = 0; reg < 4; ++reg)
      Uatt[pr * 16 + g * 4 + reg][h * 128 + n * 16 + l15] =
          (_Float16)(Oacc[n][reg] * inv_l[reg]);
  __syncthreads();

  const int* pmb = mp + b * TP + i0;
#pragma unroll
  for (int it = 0; it < 8; ++it) {
    int idx4 = it * 512 + tid;
    int r = idx4 >> 6, c = (idx4 & 63) * 4;
    float pm = (float)pmb[r];
    f32x4 hv = *(const f32x4*)&H[((size_t)b * TP + i0 + r) * D2_ + c];
    hv *= pm;
    f16x4 u4 = *(const f16x4*)&Uatt[r][c];
    f32x4 u; u.x = (float)u4[0]; u.y = (float)u4[1]; u.z = (float)u4[2]; u.w = (float)u4[3];
    size_t ro = ((size_t)b * TP + i0 + r) * (4 * D2_);
    *(f32x4*)&G[ro + c] = hv;
    f32x4 up = u * pm;
    *(f32x4*)&G[ro + D2_ + c] = up;
    f32x4 hu; hu.x = hv.x * u.x; hu.y = hv.y * u.y; hu.z = hv.z * u.z; hu.w = hv.w * u.w;
    *(f32x4*)&G[ro + 2 * D2_ + c] = hu;
  }
}

// ---------------- kernel 3a: per-batch max & sum-exp over Smax ----------------
__global__ __launch_bounds__(256) void k_smax_reduce(const float* __restrict__ Smax,
    const int* __restrict__ mp, float* __restrict__ Mb, float* __restrict__ Lb) {
  int b = blockIdx.x;
  int tid = threadIdx.x;
  const float* S = Smax + b * TP;
  const int* pm = mp + b * TP;
  __shared__ float redm[4], reds[4];
  float mx = -1e30f;
  for (int i = tid; i < TP; i += 256) mx = fmaxf(mx, S[i]);
#pragma unroll
  for (int o = 32; o; o >>= 1) mx = fmaxf(mx, __shfl_down(mx, o));
  if ((tid & 63) == 0) redm[tid >> 6] = mx;
  __syncthreads();
  mx = fmaxf(fmaxf(redm[0], redm[1]), fmaxf(redm[2], redm[3]));
  float s = 0.f;
  for (int i = tid; i < TP; i += 256) s += pm[i] ? __expf(S[i] - mx) : 0.f;
#pragma unroll
  for (int o = 32; o; o >>= 1) s += __shfl_down(s, o);
  if ((tid & 63) == 0) reds[tid >> 6] = s;
  __syncthreads();
  if (tid == 0) { Mb[b] = mx; Lb[b] = reds[0] + reds[1] + reds[2] + reds[3]; }
}

// ---------------- kernel 3b: partial h_att (deterministic) ----------------
__global__ __launch_bounds__(256) void k_hatt(const float* __restrict__ H,
    const float* __restrict__ Smax, const int* __restrict__ mp,
    const float* __restrict__ Mb, const float* __restrict__ Lb,
    float* __restrict__ partial) {
  int b = blockIdx.y;
  int chunk = blockIdx.x;
  int c = threadIdx.x;
  float mx = Mb[b];
  float inv = 1.0f / Lb[b];
  float acc = 0.f;
  int i0 = chunk * 128;
  for (int ii = 0; ii < 128; ++ii) {
    int i = i0 + ii;
    float sm = Smax[b * TP + i];
    float wgt = mp[b * TP + i] ? __expf(sm - mx) * inv : 0.f;
    acc += wgt * H[((size_t)b * TP + i) * D2_ + c];
  }
  partial[((size_t)b * 32 + chunk) * D2_ + c] = acc;
}

// ---------------- kernel 3c: sum partials -> h_att ----------------
__global__ __launch_bounds__(256) void k_hatt_sum(const float* __restrict__ partial,
                                                  float* __restrict__ hatt) {
  int b = blockIdx.x;
  int c = threadIdx.x;
  float s = 0.f;
#pragma unroll
  for (int k = 0; k < 32; ++k) s += partial[((size_t)b * 32 + k) * D2_ + c];
  hatt[b * D2_ + c] = s;
}

// ---------------- kernel 4: G slice 3 = Hm * h_att ----------------
__global__ __launch_bounds__(256) void k_g3(const float* __restrict__ H,
    const int* __restrict__ mp, const float* __restrict__ hatt,
    float* __restrict__ G) {
  const int total = B_ * TP * (D2_ / 4);
  for (int idx = blockIdx.x * 256 + threadIdx.x; idx < total; idx += gridDim.x * 256) {
    int c4 = idx & 63;
    int i = (idx >> 6) & (TP - 1);
    int b = idx >> 18;
    float pm = (float)mp[b * TP + i];
    f32x4 h = *(const f32x4*)&H[((size_t)b * TP + i) * D2_ + c4 * 4];
    f32x4 ha = *(const f32x4*)&hatt[b * D2_ + c4 * 4];
    f32x4 o;
    o.x = h.x * pm * ha.x; o.y = h.y * pm * ha.y;
    o.z = h.z * pm * ha.z; o.w = h.w * pm * ha.w;
    *(f32x4*)&G[((size_t)b * TP + i) * (4 * D2_) + 3 * D2_ + c4 * 4] = o;
  }
}

extern "C" void kernel_launch(void* const* d_in, const int* in_sizes, int n_in,
                              void* d_out, int out_size, void* d_ws, size_t ws_size,
                              hipStream_t stream) {
  const float* H  = (const float*)d_in[0];
  const float* U  = (const float*)d_in[1];
  const float* w  = (const float*)d_in[2];
  const int*   mp = (const int*)d_in[3];
  const int*   mq = (const int*)d_in[4];
  float* G = (float*)d_out;

  float* ws      = (float*)d_ws;
  float* Smax    = ws;                       // 65536
  float* Mb      = Smax + B_ * TP;           // 16
  float* Lb      = Mb + B_;                  // 16
  float* hatt    = Lb + B_;                  // 4096
  float* partial = hatt + B_ * D2_;          // 131072

  k_prep<<<dim3(NJT, B_), 256, 0, stream>>>(U, w, mq, G);
  k_main<<<dim3(TP / TI, B_), 512, 0, stream>>>(H, w, mp, Smax, G);
  k_smax_reduce<<<dim3(B_), 256, 0, stream>>>(Smax, mp, Mb, Lb);
  k_hatt<<<dim3(32, B_), 256, 0, stream>>>(H, Smax, mp, Mb, Lb, partial);
  k_hatt_sum<<<dim3(B_), 256, 0, stream>>>(partial, hatt);
  k_g3<<<dim3(2048), 256, 0, stream>>>(H, mp, hatt, G);
}